// Round 1
// 314.728 us; speedup vs baseline: 1.0855x; 1.0855x over previous
//
#include <hip/hip_runtime.h>
#include <stdint.h>

// Problem constants (from reference setup_inputs)
#define M_TOK 8192
#define N_OUT 4096
#define K_IN  4096

// GEMM tiling: 256x256 tile, BK=32, 4-deep LDS ring (128 KiB), 8 waves (2Mx4N)
#define BM 256
#define BN 256
#define BK 32
#define NT (K_IN / BK)            // 128 K-tiles
#define BUF_SHORTS 16384          // A 256*32 + B 256*32 shorts = 32 KiB
#define B_OFF 8192                // B offset within a buffer (shorts)

typedef float floatx4 __attribute__((ext_vector_type(4)));
typedef __bf16 bf16x8 __attribute__((ext_vector_type(8)));
typedef unsigned short ushort8_t __attribute__((ext_vector_type(8)));

#define MFMA16 __builtin_amdgcn_mfma_f32_16x16x32_bf16

// ---------- helpers ----------

__device__ __forceinline__ unsigned short f32_to_bf16_rne(float f) {
    union { float f; unsigned int u; } v; v.f = f;
    unsigned int u = v.u;
    u += 0x7FFFu + ((u >> 16) & 1u);   // round-to-nearest-even; inputs have no NaN
    return (unsigned short)(u >> 16);
}

// async global->LDS, 16 bytes per lane. LDS side is wave-uniform base + lane*16.
__device__ __forceinline__ void async_copy16(const void* g, void* l) {
    __builtin_amdgcn_global_load_lds(
        (__attribute__((address_space(1))) void*)(g),
        (__attribute__((address_space(3))) void*)(l),
        16, 0, 0);
}

// ---------- pre-pass: fp32 -> bf16 ----------

__global__ void cvt_f32_bf16_kernel(const float* __restrict__ in,
                                    unsigned short* __restrict__ out, int n8) {
    int i = blockIdx.x * 256 + threadIdx.x;
    if (i >= n8) return;
    const float4* p = (const float4*)in + (size_t)i * 2;
    float4 a = p[0];
    float4 b = p[1];
    ushort8_t o;
    o[0] = f32_to_bf16_rne(a.x); o[1] = f32_to_bf16_rne(a.y);
    o[2] = f32_to_bf16_rne(a.z); o[3] = f32_to_bf16_rne(a.w);
    o[4] = f32_to_bf16_rne(b.x); o[5] = f32_to_bf16_rne(b.y);
    o[6] = f32_to_bf16_rne(b.z); o[7] = f32_to_bf16_rne(b.w);
    *((ushort8_t*)out + i) = o;
}

// ---------- pre-pass: int32 (int8-valued) -> bf16 (exact) ----------

__global__ void cvt_i32_bf16_kernel(const int* __restrict__ in,
                                    unsigned short* __restrict__ out, int n8) {
    int i = blockIdx.x * 256 + threadIdx.x;
    if (i >= n8) return;
    const int4* p = (const int4*)in + (size_t)i * 2;
    int4 a = p[0];
    int4 b = p[1];
    ushort8_t o;
    o[0] = f32_to_bf16_rne((float)a.x); o[1] = f32_to_bf16_rne((float)a.y);
    o[2] = f32_to_bf16_rne((float)a.z); o[3] = f32_to_bf16_rne((float)a.w);
    o[4] = f32_to_bf16_rne((float)b.x); o[5] = f32_to_bf16_rne((float)b.y);
    o[6] = f32_to_bf16_rne((float)b.z); o[7] = f32_to_bf16_rne((float)b.w);
    *((ushort8_t*)out + i) = o;
}

// ---------- GEMM: C[m][n] = sum_k A[m][k]*B[n][k]; C = acc*scale[n]+bias[n] ----------
// A: [M][K] bf16 row-major. B: [N][K] bf16 row-major.
// 512 threads = 8 waves in 2x4; each wave owns a 128x64 output tile = acc[8][4]
// of 16x16 MFMA fragments (K=32 per MFMA call == BK, so one call per fragment
// per K-tile).
//
// Pipeline (T3+T4): 4-deep LDS ring, staging 3 K-tiles ahead. Per K-tile, two
// phases {ds_read frags + issue 2 global_load_lds -> s_barrier -> setprio(1)
// -> 16 MFMA -> setprio(0) -> s_barrier}. Boundary wait is a COUNTED
// s_waitcnt vmcnt(8): drains only tile t+1's 4 loads; tiles t+2/t+3 stay in
// flight across the barrier. Epilogue drains 8 -> 4 -> 0.
//
// LDS swizzle (T2, both-sides): LDS slot (row, cb) holds global (row,
// cb ^ ((row>>1)&3)), cb = 16 B column block in [0,4). Staging picks the
// swizzled global chunk per lane (global side of global_load_lds is per-lane);
// fragment reads XOR the same term back. Bank-slot enumeration: uniform
// 8 lanes per 4-bank group per ds_read_b128 -> conflict-free.

__global__ __launch_bounds__(512, 2)
void gemm_bf16_kernel(const unsigned short* __restrict__ A,
                      const unsigned short* __restrict__ B,
                      const float* __restrict__ scales,
                      const float* __restrict__ bias,
                      float* __restrict__ C) {
    __shared__ __align__(16) unsigned short lds[4 * BUF_SHORTS];   // 128 KiB

    const int tid = threadIdx.x;

    // T1: bijective XCD swizzle (nwg = 512, divisible by 8). n-fastest order:
    // 16 consecutive wgs share one 2 MiB A panel (L2-resident per XCD).
    const int nwg = (M_TOK / BM) * (N_OUT / BN);     // 32*16 = 512
    const int cpx = nwg / 8;                          // 64
    const int wg  = (blockIdx.x % 8) * cpx + blockIdx.x / 8;
    const int bn  = wg & 15;                          // N_OUT/BN = 16
    const int bm  = wg >> 4;                          // 0..31

    const int lane = tid & 63;
    const int wave = tid >> 6;          // 0..7
    const int wm   = wave >> 2;         // 0..1 -> rows wm*128
    const int wn   = wave & 3;          // 0..3 -> cols wn*64

    // ---- staging addressing (loop-invariant) ----
    // Per 8 KiB issue: chunk c = tid; row(within 128-row part) = tid>>2,
    // cb = tid&3, swizzled global col-block = cb ^ ((abs_row>>1)&3). Since
    // part*128 and the 64-row offset are 0 mod 4 after >>1, the XOR term is
    // (tid>>3)&3, part-independent.
    const int srow = tid >> 2;                         // 0..127
    const int gcb  = (tid & 3) ^ ((tid >> 3) & 3);
    const unsigned short* aP = A + (size_t)(bm * BM + srow) * K_IN + gcb * 8;
    const unsigned short* bP = B + (size_t)(bn * BN + srow) * K_IN + gcb * 8;

    auto stageA = [&](int tt) {
        const int bb = (tt & 3) * BUF_SHORTS;
        const unsigned short* ga = aP + (size_t)tt * BK;
        async_copy16(ga,                      &lds[bb + tid * 8]);
        async_copy16(ga + (size_t)128 * K_IN, &lds[bb + 4096 + tid * 8]);
    };
    auto stageB = [&](int tt) {
        const int bb = (tt & 3) * BUF_SHORTS;
        const unsigned short* gb = bP + (size_t)tt * BK;
        async_copy16(gb,                      &lds[bb + B_OFF + tid * 8]);
        async_copy16(gb + (size_t)128 * K_IN, &lds[bb + B_OFF + 4096 + tid * 8]);
    };

    // ---- fragment read addressing (loop-invariant) ----
    // A frag (16x16x32): row = lane&15, k = (lane>>4)*8 + j. Row stride BK.
    // Swizzle term: cbEff = q ^ ((row>>1)&3); frag row offsets (i*16) are
    // 0 mod 8 after >>1, so the XOR term is (r16>>1)&3, per-lane constant.
    const int r16 = lane & 15;
    const int q   = lane >> 4;                          // 0..3
    const int sw  = (q ^ ((r16 >> 1) & 3)) * 8;         // shorts
    const int aBase = (wm * 128 + r16) * BK + sw;
    const int bBase = B_OFF + (wn * 64 + r16) * BK + sw;

    floatx4 acc[8][4] = {};

    // ---- prologue: fill pipeline 3 tiles deep, wait only for tile 0 ----
    stageA(0); stageB(0);
    stageA(1); stageB(1);
    stageA(2); stageB(2);
    asm volatile("s_waitcnt vmcnt(8)" ::: "memory");   // tile 0's 4 loads done
    __builtin_amdgcn_s_barrier();
    asm volatile("" ::: "memory");                     // no LDS reads hoist above

    for (int t = 0; t < NT; ++t) {
        const unsigned short* ar = lds + (t & 3) * BUF_SHORTS + aBase;
        const unsigned short* br = lds + (t & 3) * BUF_SHORTS + bBase;
        bf16x8 af[4], bfr[4];

        // ---------------- phase 0: frag rows 0-3, all B cols ----------------
#pragma unroll
        for (int i = 0; i < 4; ++i) af[i]  = *(const bf16x8*)(ar + i * 512);
#pragma unroll
        for (int j = 0; j < 4; ++j) bfr[j] = *(const bf16x8*)(br + j * 512);
        if (t + 3 < NT) stageA(t + 3);     // ring slot (t+3)&3 retired at t-1
        __builtin_amdgcn_s_barrier();
        __builtin_amdgcn_s_setprio(1);
#pragma unroll
        for (int i = 0; i < 4; ++i)
#pragma unroll
            for (int j = 0; j < 4; ++j)
                acc[i][j] = MFMA16(af[i], bfr[j], acc[i][j], 0, 0, 0);
        __builtin_amdgcn_s_setprio(0);
        __builtin_amdgcn_s_barrier();

        // ---------------- phase 1: frag rows 4-7 (B reused in regs) ----------
#pragma unroll
        for (int i = 0; i < 4; ++i) af[i] = *(const bf16x8*)(ar + 2048 + i * 512);
        if (t + 3 < NT) stageB(t + 3);
        __builtin_amdgcn_s_barrier();
        __builtin_amdgcn_s_setprio(1);
#pragma unroll
        for (int i = 0; i < 4; ++i)
#pragma unroll
            for (int j = 0; j < 4; ++j)
                acc[i + 4][j] = MFMA16(af[i], bfr[j], acc[i + 4][j], 0, 0, 0);
        __builtin_amdgcn_s_setprio(0);

        // ---- tile boundary: COUNTED wait, then one barrier ----
        if (t < NT - 3) {
            asm volatile("s_waitcnt vmcnt(8)" ::: "memory");  // drain tile t+1 only
        } else if (t == NT - 3) {
            asm volatile("s_waitcnt vmcnt(4)" ::: "memory");  // epilogue drain
        } else if (t == NT - 2) {
            asm volatile("s_waitcnt vmcnt(0)" ::: "memory");
        }
        __builtin_amdgcn_s_barrier();
        asm volatile("" ::: "memory");     // next-tile ds_reads stay below
    }

    // ---- epilogue: C/D layout col = lane&15, row = (lane>>4)*4 + reg ----
    const int row_base = bm * BM + wm * 128 + q * 4;
    const int col_base = bn * BN + wn * 64 + r16;
#pragma unroll
    for (int j = 0; j < 4; ++j) {
        const int n  = col_base + j * 16;
        const float sc = scales[n];
        const float bi = bias[n];
#pragma unroll
        for (int i = 0; i < 8; ++i) {
            const int m = row_base + i * 16;
#pragma unroll
            for (int r = 0; r < 4; ++r)
                C[(size_t)(m + r) * N_OUT + n] = acc[i][j][r] * sc + bi;
        }
    }
}

// ---------- launch ----------

extern "C" void kernel_launch(void* const* d_in, const int* in_sizes, int n_in,
                              void* d_out, int out_size, void* d_ws, size_t ws_size,
                              hipStream_t stream) {
    const float* x      = (const float*)d_in[0];
    const int*   wq     = (const int*)d_in[1];
    const float* scales = (const float*)d_in[2];
    const float* bias   = (const float*)d_in[3];
    float*       out    = (float*)d_out;

    unsigned short* xb = (unsigned short*)d_ws;                       // 64 MiB
    unsigned short* wb = xb + (size_t)M_TOK * K_IN;                   // 32 MiB
    // ws needed: (8192*4096 + 4096*4096) * 2 = 96 MiB

    const int nx8 = (M_TOK * K_IN) / 8;   // 4194304
    const int nw8 = (N_OUT * K_IN) / 8;   // 2097152
    cvt_f32_bf16_kernel<<<nx8 / 256, 256, 0, stream>>>(x, xb, nx8);
    cvt_i32_bf16_kernel<<<nw8 / 256, 256, 0, stream>>>(wq, wb, nw8);

    const int grid = (M_TOK / BM) * (N_OUT / BN);   // 32 * 16 = 512
    gemm_bf16_kernel<<<grid, 512, 0, stream>>>(xb, wb, scales, bias, out);
}